// Round 7
// baseline (3125.464 us; speedup 1.0000x reference)
//
#include <hip/hip_runtime.h>
#include <hip/hip_bf16.h>
#include <hip/hip_fp16.h>

#define HDIM 50
#define G3   150
#define TSEQ 512
#define BATCH 2048
#define WCH  7     // uint4 chunks per weight row (7*8 = 56 f16, j>=50 zero)
#define NPAIR 28   // half2 pairs per row (56 f16)

typedef _Float16 half2_t __attribute__((ext_vector_type(2)));

#if __has_builtin(__builtin_amdgcn_fdot2)
#define FDOT2(a, b, c) __builtin_amdgcn_fdot2((a), (b), (c), false)
#else
static __device__ inline float FDOT2(half2_t a, half2_t b, float c) {
    return c + (float)a.x * (float)b.x + (float)a.y * (float)b.y;
}
#endif

static __device__ inline half2_t bc_h2(unsigned int u) {
    return __builtin_bit_cast(half2_t, u);
}

// act[t][b][i] = t*(BATCH*HDIM) + b*HDIM + i   (209,715,200 B in d_ws)

template<int IN_DIM, int NB>
__global__ __launch_bounds__(192)
void gru_layer_kernel(const float* __restrict__ xin_g,   // IN_DIM==1: x [B][T]; else act [T][B][H] (in-place ok)
                      float* __restrict__ act,
                      const float* __restrict__ Wih,
                      const float* __restrict__ Whh,
                      const float* __restrict__ bih,
                      const float* __restrict__ bhh)
{
    const int tid = threadIdx.x;
    const int b0  = blockIdx.x * NB;
    const int row = (tid < G3) ? tid : (G3 - 1);

    // f16 weights, chunk-major: w4[c*G3 + row] = 8 f16 of row `row`, j = 8c..8c+7.
    // Lane(=row)-consecutive uint4 reads -> conflict-free ds_read_b128.
    __shared__ uint4 whh4[WCH * G3];
    __shared__ uint4 wih4[(IN_DIM==1) ? 1 : (WCH * G3)];
    __shared__ float wih_s[(IN_DIM==1) ? G3 : 1];     // layer-0 scalar weights (f32)
    __shared__ __align__(16) half2_t h_s[NB][NPAIR];  // h as f16 pairs, pads zero
    __shared__ __align__(16) half2_t x_s[(IN_DIM==1) ? 1 : NB][NPAIR];
    __shared__ float s_rz[NB][100];
    __shared__ float s_xn[NB][50];
    __shared__ float s_hn[NB][50];
    __shared__ float x_row[(IN_DIM==1) ? NB : 1][(IN_DIM==1) ? TSEQ : 1];

    // ---- one-time staging: weights f32 -> f16 pairs in LDS ----
    for (int k = tid; k < G3 * NPAIR; k += 192) {
        const int r = k % G3;          // weight row
        const int p = k / G3;          // pair index 0..27, j = 2p
        const int j = 2 * p;
        const int c = p >> 2, sub = p & 3;
        {
            float a = (j     < HDIM) ? Whh[r*HDIM + j    ] : 0.f;
            float b = (j + 1 < HDIM) ? Whh[r*HDIM + j + 1] : 0.f;
            half2_t hp; hp.x = (_Float16)a; hp.y = (_Float16)b;
            ((unsigned int*)&whh4[c*G3 + r])[sub] = __builtin_bit_cast(unsigned int, hp);
        }
        if constexpr (IN_DIM != 1) {
            float a = (j     < IN_DIM) ? Wih[r*IN_DIM + j    ] : 0.f;
            float b = (j + 1 < IN_DIM) ? Wih[r*IN_DIM + j + 1] : 0.f;
            half2_t hp; hp.x = (_Float16)a; hp.y = (_Float16)b;
            ((unsigned int*)&wih4[c*G3 + r])[sub] = __builtin_bit_cast(unsigned int, hp);
        }
    }
    if constexpr (IN_DIM == 1) {
        if (tid < G3) wih_s[tid] = Wih[tid];
        for (int k = tid; k < NB*TSEQ; k += 192)
            x_row[k/TSEQ][k%TSEQ] = xin_g[(size_t)(b0 + k/TSEQ)*TSEQ + (k%TSEQ)];
    }
    const float b_i = bih[row];
    const float b_h = bhh[row];

    // h = 0 (and pads); x_s pads = 0
    for (int k = tid; k < NB*NPAIR; k += 192) { half2_t z; z.x = (_Float16)0.f; z.y = (_Float16)0.f; h_s[k/NPAIR][k%NPAIR] = z; }
    if constexpr (IN_DIM != 1) {
        for (int k = tid; k < NB*NPAIR; k += 192) { half2_t z; z.x = (_Float16)0.f; z.y = (_Float16)0.f; x_s[k/NPAIR][k%NPAIR] = z; }
    }

    float xpre = 0.f;
    if (IN_DIM != 1 && tid < NB*HDIM) {
        xpre = xin_g[(size_t)(b0 + tid/HDIM)*HDIM + (tid%HDIM)];
    }
    __syncthreads();

    for (int t = 0; t < TSEQ; ++t) {
        // ---- stage 1: publish x(t) as f16; prefetch x(t+1) ----
        if constexpr (IN_DIM != 1) {
            if (tid < NB*HDIM)
                ((_Float16*)&x_s[tid/HDIM][0])[tid%HDIM] = (_Float16)xpre;
        }
        __syncthreads();
        if (IN_DIM != 1 && tid < NB*HDIM && t+1 < TSEQ) {
            xpre = xin_g[(size_t)(t+1)*(BATCH*HDIM) + (size_t)(b0 + tid/HDIM)*HDIM + (tid%HDIM)];
        }

        // ---- stage 2: gate GEMV via fdot2, weights/operands from LDS ----
        if (tid < G3) {
            const uint4* wp = &whh4[tid];
#pragma unroll
            for (int b = 0; b < NB; ++b) {
                float gh = b_h;
                const uint4* hp = (const uint4*)&h_s[b][0];
#pragma unroll
                for (int c = 0; c < WCH; ++c) {
                    uint4 w = wp[c*G3];
                    uint4 h = hp[c];
                    gh = FDOT2(bc_h2(w.x), bc_h2(h.x), gh);
                    gh = FDOT2(bc_h2(w.y), bc_h2(h.y), gh);
                    gh = FDOT2(bc_h2(w.z), bc_h2(h.z), gh);
                    gh = FDOT2(bc_h2(w.w), bc_h2(h.w), gh);
                }
                float gx = b_i;
                if constexpr (IN_DIM == 1) {
                    gx = fmaf(wih_s[tid], x_row[b][t], gx);
                } else {
                    const uint4* ip = &wih4[tid];
                    const uint4* xp = (const uint4*)&x_s[b][0];
#pragma unroll
                    for (int c = 0; c < WCH; ++c) {
                        uint4 w = ip[c*G3];
                        uint4 x = xp[c];
                        gx = FDOT2(bc_h2(w.x), bc_h2(x.x), gx);
                        gx = FDOT2(bc_h2(w.y), bc_h2(x.y), gx);
                        gx = FDOT2(bc_h2(w.z), bc_h2(x.z), gx);
                        gx = FDOT2(bc_h2(w.w), bc_h2(x.w), gx);
                    }
                }
                if (tid < 100) {
                    s_rz[b][tid] = gx + gh;
                } else {
                    s_xn[b][tid-100] = gx;
                    s_hn[b][tid-100] = gh;
                }
            }
        }
        __syncthreads();

        // ---- stage 3: gate update; h' -> LDS(f16) + global(f32) ----
        if (tid < NB*HDIM) {
            const int b = tid / HDIM, u = tid % HDIM;
            float r = 1.f / (1.f + __expf(-s_rz[b][u]));
            float z = 1.f / (1.f + __expf(-s_rz[b][u+50]));
            float v = s_xn[b][u] + r * s_hn[b][u];
            v = fminf(fmaxf(v, -15.f), 15.f);
            float e = __expf(2.f * v);
            float n = (e - 1.f) / (e + 1.f);          // tanh(v), clamped so e finite
            float hold = (float)(((const _Float16*)&h_s[b][0])[u]);
            float hn = (1.f - z)*n + z*hold;
            ((_Float16*)&h_s[b][0])[u] = (_Float16)hn;
            act[(size_t)t*(BATCH*HDIM) + (size_t)(b0 + b)*HDIM + u] = hn;
        }
    }
}

__global__ __launch_bounds__(256)
void fc_sigmoid_kernel(const float* __restrict__ act,
                       const float* __restrict__ fcw,
                       const float* __restrict__ fcb,
                       float* __restrict__ out)
{
    int b = blockIdx.x*256 + threadIdx.x;
    if (b >= BATCH) return;
    const float* row = act + (size_t)(TSEQ-1)*(BATCH*HDIM) + (size_t)b*HDIM;
    float s = fcb[0];
#pragma unroll
    for (int j = 0; j < HDIM; ++j) s = fmaf(row[j], fcw[j], s);
    out[b] = 1.f / (1.f + __expf(-s));
}

extern "C" void kernel_launch(void* const* d_in, const int* in_sizes, int n_in,
                              void* d_out, int out_size, void* d_ws, size_t ws_size,
                              hipStream_t stream) {
    const float* x     = (const float*)d_in[0];
    const float* W_ih0 = (const float*)d_in[1];
    const float* W_hh0 = (const float*)d_in[2];
    const float* b_ih0 = (const float*)d_in[3];
    const float* b_hh0 = (const float*)d_in[4];
    const float* W_ih  = (const float*)d_in[5];
    const float* W_hh  = (const float*)d_in[6];
    const float* b_ih  = (const float*)d_in[7];
    const float* b_hh  = (const float*)d_in[8];
    const float* fc_w  = (const float*)d_in[9];
    const float* fc_b  = (const float*)d_in[10];
    float* out = (float*)d_out;

    float* act = (float*)d_ws;   // [512][2048][50] fp32

    constexpr int NB = 2;
    dim3 grid(BATCH / NB), block(192);

    gru_layer_kernel<1, NB><<<grid, block, 0, stream>>>(x, act, W_ih0, W_hh0, b_ih0, b_hh0);
    for (int l = 0; l < 3; ++l) {
        gru_layer_kernel<HDIM, NB><<<grid, block, 0, stream>>>(
            act, act,
            W_ih + (size_t)l*G3*HDIM, W_hh + (size_t)l*G3*HDIM,
            b_ih + (size_t)l*G3,      b_hh + (size_t)l*G3);
    }
    fc_sigmoid_kernel<<<BATCH/256, 256, 0, stream>>>(act, fc_w, fc_b, out);
}

// Round 8
// 2262.412 us; speedup vs baseline: 1.3815x; 1.3815x over previous
//
#include <hip/hip_runtime.h>
#include <hip/hip_fp16.h>

#define HDIM  50
#define G3    150
#define TSEQ  512
#define BATCH 2048
#define NB    16       // batches per block
#define ACT_K 64       // padded feature dim of act rows (f16)

typedef _Float16 f16x8 __attribute__((ext_vector_type(8)));
typedef _Float16 f16x2 __attribute__((ext_vector_type(2)));
typedef float    f32x4 __attribute__((ext_vector_type(4)));

#define MFMA(a,b,c) __builtin_amdgcn_mfma_f32_16x16x32_f16((a),(b),(c),0,0,0)

// act layout: act[t][b][k], k in [0,64): k<50 = h value, k==50 = 1.0 (bias slot),
// k>50 = 0.  Stored f16.  Size = 512*2048*64*2 = 134 MB (d_ws).

template<int IN_DIM>
__global__ __launch_bounds__(192)
void gru_mfma_kernel(const float* __restrict__ xin,   // IN_DIM==1: x [B][T] f32
                     _Float16* __restrict__ act,      // [T][B][64] f16 (in/out, in-place across layers)
                     const float* __restrict__ Wih,   // [150][IN_DIM]
                     const float* __restrict__ Whh,   // [150][50]
                     const float* __restrict__ bih,   // [150]
                     const float* __restrict__ bhh)   // [150]
{
    const int tid  = threadIdx.x;
    const int wid  = tid >> 6;     // wave 0:r  1:z  2:n
    const int lane = tid & 63;
    const int lb   = lane & 15;    // A: m-in-tile; B: batch col; C: batch col
    const int lg   = lane >> 4;    // k-octet group (A/B), m-subgroup (C)
    const int b0   = blockIdx.x * NB;

    __shared__ __align__(16) _Float16 h_lds[NB][72];   // [batch][k], stride 72 spreads banks
    __shared__ unsigned rz_buf[2][32][NB];             // [r/z][u>>1][batch], f16x2 packed

    // ---- A fragments: weights resident in VGPRs, loaded once ----
    // a[mt][kt] lane layout: A[m = 16*mt + (lane&15)][k = 32*kt + 8*(lane>>4) + j]
    // bias folded at k==50 (pairs with h[50] = x[50] = 1.0).
    f16x8 a_hh[4][2];
    f16x8 a_ih[4][(IN_DIM==1) ? 1 : 2];
#pragma unroll
    for (int mt = 0; mt < 4; ++mt) {
        const int  rl = 16*mt + lb;
        const bool rv = rl < HDIM;
        const int  gr = 50*wid + (rv ? rl : 0);
#pragma unroll
        for (int kt = 0; kt < 2; ++kt) {
            f16x8 f;
#pragma unroll
            for (int j = 0; j < 8; ++j) {
                const int k = 32*kt + 8*lg + j;
                float v = 0.f;
                if (rv) { if (k < HDIM) v = Whh[gr*HDIM + k]; else if (k == HDIM) v = bhh[gr]; }
                f[j] = (_Float16)v;
            }
            a_hh[mt][kt] = f;
        }
        if constexpr (IN_DIM == 1) {
            f16x8 f;
#pragma unroll
            for (int j = 0; j < 8; ++j) {
                const int k = 8*lg + j;
                float v = 0.f;
                if (rv) { if (k == 0) v = Wih[gr]; else if (k == 1) v = bih[gr]; }
                f[j] = (_Float16)v;
            }
            a_ih[mt][0] = f;
        } else {
#pragma unroll
            for (int kt = 0; kt < 2; ++kt) {
                f16x8 f;
#pragma unroll
                for (int j = 0; j < 8; ++j) {
                    const int k = 32*kt + 8*lg + j;
                    float v = 0.f;
                    if (rv) { if (k < HDIM) v = Wih[gr*HDIM + k]; else if (k == HDIM) v = bih[gr]; }
                    f[j] = (_Float16)v;
                }
                a_ih[mt][kt] = f;
            }
        }
    }

    // persistent h in C-layout (wave2 uses): hold[mt][i] = h[u = 16mt+4lg+i][b=lb]
    float hold[4][4];
#pragma unroll
    for (int mt = 0; mt < 4; ++mt)
#pragma unroll
        for (int i = 0; i < 4; ++i) hold[mt][i] = 0.f;

    // init h_lds: h=0, slot 50 = 1.0 (bias), rest 0
    for (int k2 = tid; k2 < NB*72; k2 += 192)
        h_lds[k2/72][k2%72] = (_Float16)((k2%72) == HDIM ? 1.f : 0.f);
    __syncthreads();

    // B-fragments of h: lane reads h[k = 32*kt + 8*lg + j][b = lb]
    f16x8 bh0 = *(const f16x8*)&h_lds[lb][8*lg];
    f16x8 bh1 = *(const f16x8*)&h_lds[lb][32 + 8*lg];

    // x prefetch (t = 0)
    f16x8 xf0{}, xf1{};
    float xvf = 0.f;
    if constexpr (IN_DIM == 1) {
        xvf = xin[(size_t)(b0 + lb)*TSEQ + 0];
    } else {
        const _Float16* src = act + ((size_t)0*BATCH + b0 + lb)*ACT_K + 8*lg;
        xf0 = *(const f16x8*)src;
        xf1 = *(const f16x8*)(src + 32);
    }

    for (int t = 0; t < TSEQ; ++t) {
        // current x fragments
        f16x8 bx0, bx1{};
        if constexpr (IN_DIM == 1) {
#pragma unroll
            for (int j = 0; j < 8; ++j) bx0[j] = (_Float16)0.f;
            if (lg == 0) { bx0[0] = (_Float16)xvf; bx0[1] = (_Float16)1.f; }
        } else { bx0 = xf0; bx1 = xf1; }

        // prefetch x(t+1)  (in-place safe: row t+1 not yet overwritten)
        const int tn = (t+1 < TSEQ) ? t+1 : t;
        if constexpr (IN_DIM == 1) {
            xvf = xin[(size_t)(b0 + lb)*TSEQ + tn];
        } else {
            const _Float16* src = act + ((size_t)tn*BATCH + b0 + lb)*ACT_K + 8*lg;
            xf0 = *(const f16x8*)src;
            xf1 = *(const f16x8*)(src + 32);
        }

        f32x4 acc_a[4], acc_b[4];   // wave0/1: acc_a = gate pre-act; wave2: a=gh_n, b=gx_n
#pragma unroll
        for (int mt = 0; mt < 4; ++mt) { acc_a[mt] = f32x4{0.f,0.f,0.f,0.f}; acc_b[mt] = f32x4{0.f,0.f,0.f,0.f}; }

        if (wid < 2) {
#pragma unroll
            for (int mt = 0; mt < 4; ++mt) acc_a[mt] = MFMA(a_hh[mt][0], bh0, acc_a[mt]);
#pragma unroll
            for (int mt = 0; mt < 4; ++mt) acc_a[mt] = MFMA(a_hh[mt][1], bh1, acc_a[mt]);
#pragma unroll
            for (int mt = 0; mt < 4; ++mt) acc_a[mt] = MFMA(a_ih[mt][0], bx0, acc_a[mt]);
            if constexpr (IN_DIM != 1) {
#pragma unroll
                for (int mt = 0; mt < 4; ++mt) acc_a[mt] = MFMA(a_ih[mt][1], bx1, acc_a[mt]);
            }
            // sigmoid, pack f16 pairs, publish
#pragma unroll
            for (int mt = 0; mt < 4; ++mt) {
#pragma unroll
                for (int ip = 0; ip < 2; ++ip) {
                    float v0 = acc_a[mt][2*ip+0], v1 = acc_a[mt][2*ip+1];
                    float s0 = __builtin_amdgcn_rcpf(1.f + __expf(-v0));
                    float s1 = __builtin_amdgcn_rcpf(1.f + __expf(-v1));
                    f16x2 p; p[0] = (_Float16)s0; p[1] = (_Float16)s1;
                    rz_buf[wid][8*mt + 2*lg + ip][lb] = __builtin_bit_cast(unsigned, p);
                }
            }
        } else {
#pragma unroll
            for (int mt = 0; mt < 4; ++mt) acc_a[mt] = MFMA(a_hh[mt][0], bh0, acc_a[mt]);
#pragma unroll
            for (int mt = 0; mt < 4; ++mt) acc_a[mt] = MFMA(a_hh[mt][1], bh1, acc_a[mt]);
#pragma unroll
            for (int mt = 0; mt < 4; ++mt) acc_b[mt] = MFMA(a_ih[mt][0], bx0, acc_b[mt]);
            if constexpr (IN_DIM != 1) {
#pragma unroll
                for (int mt = 0; mt < 4; ++mt) acc_b[mt] = MFMA(a_ih[mt][1], bx1, acc_b[mt]);
            }
        }
        __syncthreads();   // A: r,z published

        if (wid == 2) {
#pragma unroll
            for (int mt = 0; mt < 4; ++mt) {
#pragma unroll
                for (int ip = 0; ip < 2; ++ip) {
                    const int u = 16*mt + 4*lg + 2*ip;
                    f16x2 rp = __builtin_bit_cast(f16x2, rz_buf[0][8*mt + 2*lg + ip][lb]);
                    f16x2 zp = __builtin_bit_cast(f16x2, rz_buf[1][8*mt + 2*lg + ip][lb]);
                    float hp01[2];
#pragma unroll
                    for (int e = 0; e < 2; ++e) {
                        const int i = 2*ip + e;
                        float r = (float)rp[e], z = (float)zp[e];
                        float vp = acc_b[mt][i] + r*acc_a[mt][i];
                        float e2 = __expf(2.f*vp);
                        float n  = 1.f - 2.f*__builtin_amdgcn_rcpf(e2 + 1.f);  // tanh(vp)
                        float hp = fmaf(z, hold[mt][i] - n, n);                // (1-z)n + z h
                        hold[mt][i] = hp;
                        hp01[e] = hp;
                    }
                    if (u < HDIM) {   // never touch bias slot 50 / zero pads
                        f16x2 hq; hq[0] = (_Float16)hp01[0]; hq[1] = (_Float16)hp01[1];
                        *(f16x2*)&h_lds[lb][u] = hq;
                    }
                }
            }
        }
        __syncthreads();   // B: h(t) ready

        bh0 = *(const f16x8*)&h_lds[lb][8*lg];
        bh1 = *(const f16x8*)&h_lds[lb][32 + 8*lg];
        if (wid == 0) {    // mirror h(t) to act[t] (coalesced 2x dwordx4)
            _Float16* dst = act + ((size_t)t*BATCH + b0 + lb)*ACT_K + 8*lg;
            *(f16x8*)dst        = bh0;
            *(f16x8*)(dst + 32) = bh1;
        }
    }
}

__global__ __launch_bounds__(256)
void fc_sigmoid_kernel(const _Float16* __restrict__ act,
                       const float* __restrict__ fcw,
                       const float* __restrict__ fcb,
                       float* __restrict__ out)
{
    int b = blockIdx.x*256 + threadIdx.x;
    if (b >= BATCH) return;
    const _Float16* row = act + ((size_t)(TSEQ-1)*BATCH + b)*ACT_K;
    float s = fcb[0];
#pragma unroll
    for (int j = 0; j < HDIM; ++j) s = fmaf((float)row[j], fcw[j], s);
    out[b] = __builtin_amdgcn_rcpf(1.f + __expf(-s));
}

extern "C" void kernel_launch(void* const* d_in, const int* in_sizes, int n_in,
                              void* d_out, int out_size, void* d_ws, size_t ws_size,
                              hipStream_t stream) {
    const float* x     = (const float*)d_in[0];   // [2048][512][1]
    const float* W_ih0 = (const float*)d_in[1];   // [150][1]
    const float* W_hh0 = (const float*)d_in[2];   // [150][50]
    const float* b_ih0 = (const float*)d_in[3];
    const float* b_hh0 = (const float*)d_in[4];
    const float* W_ih  = (const float*)d_in[5];   // [3][150][50]
    const float* W_hh  = (const float*)d_in[6];   // [3][150][50]
    const float* b_ih  = (const float*)d_in[7];   // [3][150]
    const float* b_hh  = (const float*)d_in[8];   // [3][150]
    const float* fc_w  = (const float*)d_in[9];   // [1][50]
    const float* fc_b  = (const float*)d_in[10];  // [1]
    float* out = (float*)d_out;

    _Float16* act = (_Float16*)d_ws;   // [512][2048][64] f16 = 134 MB

    dim3 grid(BATCH / NB), block(192);

    gru_mfma_kernel<1><<<grid, block, 0, stream>>>(x, act, W_ih0, W_hh0, b_ih0, b_hh0);
    for (int l = 0; l < 3; ++l) {
        gru_mfma_kernel<HDIM><<<grid, block, 0, stream>>>(
            nullptr, act,
            W_ih + (size_t)l*G3*HDIM, W_hh + (size_t)l*G3*HDIM,
            b_ih + (size_t)l*G3,      b_hh + (size_t)l*G3);
    }
    fc_sigmoid_kernel<<<BATCH/256, 256, 0, stream>>>(act, fc_w, fc_b, out);
}

// Round 9
// 695.420 us; speedup vs baseline: 4.4944x; 3.2533x over previous
//
#include <hip/hip_runtime.h>
#include <hip/hip_fp16.h>

#define HDIM  50
#define G3    150
#define TSEQ  512
#define BATCH 2048
#define NB    8        // real batches per block (MFMA cols 0..7; 8..15 mirror col 7)
#define NLAY  4

typedef _Float16 f16x8 __attribute__((ext_vector_type(8)));
typedef _Float16 f16x2 __attribute__((ext_vector_type(2)));
typedef float    f32x4 __attribute__((ext_vector_type(4)));

#define MFMA(a,b,c) __builtin_amdgcn_mfma_f32_16x16x32_f16((a),(b),(c),0,0,0)

// Fused 4-layer GRU, wavefront-pipelined over timesteps:
// global step s: layer l computes its t = s - l (515 steps total).
// Inter-layer handoff via h_lds[l] (f16, bias slot k=50 == 1.0, so the
// consumer's b_ih folded at weight col 50 is applied for free).
__global__ __launch_bounds__(768)
void gru_fused_kernel(const float* __restrict__ xin,    // [B][T] f32
                      const float* __restrict__ Wih0,   // [150][1]
                      const float* __restrict__ Whh0,   // [150][50]
                      const float* __restrict__ bih0,
                      const float* __restrict__ bhh0,
                      const float* __restrict__ WihL,   // [3][150][50]
                      const float* __restrict__ WhhL,   // [3][150][50]
                      const float* __restrict__ bihL,   // [3][150]
                      const float* __restrict__ bhhL,
                      const float* __restrict__ fcw,    // [50]
                      const float* __restrict__ fcb,    // [1]
                      float* __restrict__ out)          // [2048] f32
{
    const int tid  = threadIdx.x;
    const int wid  = tid >> 6;
    const int lay  = wid / 3;       // 0..3
    const int role = wid % 3;       // 0:r 1:z 2:n
    const int lane = tid & 63;
    const int lb   = lane & 15;     // batch col
    const int lg   = lane >> 4;     // k-octet group / m-subgroup
    const int b0   = blockIdx.x * NB;
    const int bb   = b0 + ((lb < NB) ? lb : (NB - 1));   // clamped batch for global x

    __shared__ __align__(16) _Float16 h_lds[NLAY][16][72];   // [layer][batch][k], k=50 is 1.0
    __shared__ unsigned rz_buf[NLAY][2][32][16];             // [layer][r/z][u>>1][batch] f16x2

    // per-layer weight views
    const float* Wih = (lay == 0) ? Wih0 : (WihL + (size_t)(lay-1)*G3*HDIM);
    const float* Whh = (lay == 0) ? Whh0 : (WhhL + (size_t)(lay-1)*G3*HDIM);
    const float* bih = (lay == 0) ? bih0 : (bihL + (lay-1)*G3);
    const float* bhh = (lay == 0) ? bhh0 : (bhhL + (lay-1)*G3);

    // ---- A fragments (weights + folded biases), resident for whole kernel ----
    // a[mt][kt]: A[m = 16*mt + (lane&15)][k = 32*kt + 8*(lane>>4) + j]; gate rows 50*role+m.
    f16x8 a_hh[4][2], a_ih[4][2];
#pragma unroll
    for (int mt = 0; mt < 4; ++mt) {
        const int  rl = 16*mt + lb;
        const bool rv = rl < HDIM;
        const int  gr = 50*role + (rv ? rl : 0);
#pragma unroll
        for (int kt = 0; kt < 2; ++kt) {
            f16x8 fh, fi;
#pragma unroll
            for (int j = 0; j < 8; ++j) {
                const int k = 32*kt + 8*lg + j;
                float vh = 0.f, vi = 0.f;
                if (rv) {
                    if (k < HDIM) vh = Whh[gr*HDIM + k]; else if (k == HDIM) vh = bhh[gr];
                    if (lay == 0) {
                        if (kt == 0 && k == 0) vi = Wih[gr];
                        else if (kt == 0 && k == 1) vi = bih[gr];
                    } else {
                        if (k < HDIM) vi = Wih[gr*HDIM + k]; else if (k == HDIM) vi = bih[gr];
                    }
                }
                fh[j] = (_Float16)vh; fi[j] = (_Float16)vi;
            }
            a_hh[mt][kt] = fh; a_ih[mt][kt] = fi;
        }
    }

    // persistent h in C-layout (n-wave): hold[mt][i] = h[u=16mt+4lg+i][b=lb]
    float hold[4][4];
#pragma unroll
    for (int mt = 0; mt < 4; ++mt)
#pragma unroll
        for (int i = 0; i < 4; ++i) hold[mt][i] = 0.f;

    // init h_lds: h=0, bias slot 50 = 1.0
    for (int k2 = tid; k2 < NLAY*16*72; k2 += 768) {
        const int l = k2 / (16*72), r = k2 % (16*72);
        h_lds[l][r/72][r%72] = (_Float16)((r%72) == HDIM ? 1.f : 0.f);
    }
    __syncthreads();

    // initial fragments
    f16x8 bh0 = *(const f16x8*)&h_lds[lay][lb][8*lg];
    f16x8 bh1 = *(const f16x8*)&h_lds[lay][lb][32 + 8*lg];
    f16x8 bx0{}, bx1{};
    float xv_use = 0.f, xv_nxt = 0.f;
    if (lay == 0) {
        xv_use = xin[(size_t)bb*TSEQ + 0];
        xv_nxt = xin[(size_t)bb*TSEQ + 1];
#pragma unroll
        for (int j = 0; j < 8; ++j) bx0[j] = (_Float16)0.f;
        if (lg == 0) { bx0[0] = (_Float16)xv_use; bx0[1] = (_Float16)1.f; }
    } else {
        bx0 = *(const f16x8*)&h_lds[lay-1][lb][8*lg];        // zeros + bias slot
        bx1 = *(const f16x8*)&h_lds[lay-1][lb][32 + 8*lg];
    }

    for (int s = 0; s < TSEQ + NLAY - 1; ++s) {
        const int  t       = s - lay;
        const bool act_now = (t >= 0) && (t < TSEQ);

        f32x4 acc_a[4], acc_b[4];
        if (act_now) {
#pragma unroll
            for (int mt = 0; mt < 4; ++mt) { acc_a[mt] = f32x4{0.f,0.f,0.f,0.f}; acc_b[mt] = f32x4{0.f,0.f,0.f,0.f}; }
            if (role < 2) {
#pragma unroll
                for (int mt = 0; mt < 4; ++mt) acc_a[mt] = MFMA(a_hh[mt][0], bh0, acc_a[mt]);
#pragma unroll
                for (int mt = 0; mt < 4; ++mt) acc_a[mt] = MFMA(a_hh[mt][1], bh1, acc_a[mt]);
#pragma unroll
                for (int mt = 0; mt < 4; ++mt) acc_a[mt] = MFMA(a_ih[mt][0], bx0, acc_a[mt]);
                if (lay != 0) {
#pragma unroll
                    for (int mt = 0; mt < 4; ++mt) acc_a[mt] = MFMA(a_ih[mt][1], bx1, acc_a[mt]);
                }
                // sigmoid, publish r/z
#pragma unroll
                for (int mt = 0; mt < 4; ++mt) {
#pragma unroll
                    for (int ip = 0; ip < 2; ++ip) {
                        float v0 = acc_a[mt][2*ip+0], v1 = acc_a[mt][2*ip+1];
                        float s0 = __builtin_amdgcn_rcpf(1.f + __expf(-v0));
                        float s1 = __builtin_amdgcn_rcpf(1.f + __expf(-v1));
                        f16x2 p; p[0] = (_Float16)s0; p[1] = (_Float16)s1;
                        rz_buf[lay][role][8*mt + 2*lg + ip][lb] = __builtin_bit_cast(unsigned, p);
                    }
                }
            } else {
#pragma unroll
                for (int mt = 0; mt < 4; ++mt) acc_a[mt] = MFMA(a_hh[mt][0], bh0, acc_a[mt]);
#pragma unroll
                for (int mt = 0; mt < 4; ++mt) acc_a[mt] = MFMA(a_hh[mt][1], bh1, acc_a[mt]);
#pragma unroll
                for (int mt = 0; mt < 4; ++mt) acc_b[mt] = MFMA(a_ih[mt][0], bx0, acc_b[mt]);
                if (lay != 0) {
#pragma unroll
                    for (int mt = 0; mt < 4; ++mt) acc_b[mt] = MFMA(a_ih[mt][1], bx1, acc_b[mt]);
                }
            }
        }
        __syncthreads();   // r,z published

        if (act_now && role == 2) {
#pragma unroll
            for (int mt = 0; mt < 4; ++mt) {
#pragma unroll
                for (int ip = 0; ip < 2; ++ip) {
                    const int u = 16*mt + 4*lg + 2*ip;
                    f16x2 rp = __builtin_bit_cast(f16x2, rz_buf[lay][0][8*mt + 2*lg + ip][lb]);
                    f16x2 zp = __builtin_bit_cast(f16x2, rz_buf[lay][1][8*mt + 2*lg + ip][lb]);
                    float hp01[2];
#pragma unroll
                    for (int e = 0; e < 2; ++e) {
                        const int i = 2*ip + e;
                        float r = (float)rp[e], z = (float)zp[e];
                        float vp = acc_b[mt][i] + r*acc_a[mt][i];
                        float e2 = __expf(2.f*vp);
                        float n  = 1.f - 2.f*__builtin_amdgcn_rcpf(e2 + 1.f);  // tanh
                        float hp = fmaf(z, hold[mt][i] - n, n);                // (1-z)n+zh
                        hold[mt][i] = hp;
                        hp01[e] = hp;
                    }
                    if (u < HDIM) {
                        f16x2 hq; hq[0] = (_Float16)hp01[0]; hq[1] = (_Float16)hp01[1];
                        *(f16x2*)&h_lds[lay][lb][u] = hq;
                    }
                }
            }
        }
        __syncthreads();   // h(t) visible

        // refresh fragments for step s+1
        bh0 = *(const f16x8*)&h_lds[lay][lb][8*lg];
        bh1 = *(const f16x8*)&h_lds[lay][lb][32 + 8*lg];
        if (lay == 0) {
            xv_use = xv_nxt;
            const int tp = (s+2 <= TSEQ-1) ? s+2 : (TSEQ-1);
            xv_nxt = xin[(size_t)bb*TSEQ + tp];
#pragma unroll
            for (int j = 0; j < 8; ++j) bx0[j] = (_Float16)0.f;
            if (lg == 0) { bx0[0] = (_Float16)xv_use; bx0[1] = (_Float16)1.f; }
        } else {
            bx0 = *(const f16x8*)&h_lds[lay-1][lb][8*lg];
            bx1 = *(const f16x8*)&h_lds[lay-1][lb][32 + 8*lg];
        }
    }

    // ---- fused FC + sigmoid on layer-3 final h ----
    if (wid == 0 && lane < NB) {
        float sacc = fcb[0];
#pragma unroll
        for (int j = 0; j < HDIM; ++j)
            sacc = fmaf((float)h_lds[NLAY-1][lane][j], fcw[j], sacc);
        out[b0 + lane] = __builtin_amdgcn_rcpf(1.f + __expf(-sacc));
    }
}

extern "C" void kernel_launch(void* const* d_in, const int* in_sizes, int n_in,
                              void* d_out, int out_size, void* d_ws, size_t ws_size,
                              hipStream_t stream) {
    const float* x     = (const float*)d_in[0];
    const float* W_ih0 = (const float*)d_in[1];
    const float* W_hh0 = (const float*)d_in[2];
    const float* b_ih0 = (const float*)d_in[3];
    const float* b_hh0 = (const float*)d_in[4];
    const float* W_ih  = (const float*)d_in[5];
    const float* W_hh  = (const float*)d_in[6];
    const float* b_ih  = (const float*)d_in[7];
    const float* b_hh  = (const float*)d_in[8];
    const float* fc_w  = (const float*)d_in[9];
    const float* fc_b  = (const float*)d_in[10];
    float* out = (float*)d_out;

    dim3 grid(BATCH / NB), block(768);
    gru_fused_kernel<<<grid, block, 0, stream>>>(
        x, W_ih0, W_hh0, b_ih0, b_hh0,
        W_ih, W_hh, b_ih, b_hh, fc_w, fc_b, out);
}

// Round 10
// 621.113 us; speedup vs baseline: 5.0320x; 1.1196x over previous
//
#include <hip/hip_runtime.h>
#include <hip/hip_fp16.h>

#define HDIM  50
#define G3    150
#define TSEQ  512
#define BATCH 2048
#define NB    8        // real batches per block (MFMA cols 0..7; 8..15 mirror col 7)
#define NLAY  4
#define NT    12       // A-row tiles: 0-3 = r rows 0..63, 4-7 = z, 8-11 = n (50 real/64)

typedef _Float16 f16x8 __attribute__((ext_vector_type(8)));
typedef _Float16 f16x2 __attribute__((ext_vector_type(2)));
typedef float    f32x4 __attribute__((ext_vector_type(4)));

#define MFMA(a,b,c) __builtin_amdgcn_mfma_f32_16x16x32_f16((a),(b),(c),0,0,0)

// One wave per layer, all three gates per wave (gate blocks tile-aligned so
// r[u], z[u], gh_n[u], gx_n[u] share a lane at tile offsets m, m+4, m+8).
// One barrier per pipeline step; h handoff via parity double-buffered LDS.
__global__ __launch_bounds__(256, 1)
void gru_fused1w(const float* __restrict__ xin,    // [B][T] f32
                 const float* __restrict__ Wih0, const float* __restrict__ Whh0,
                 const float* __restrict__ bih0, const float* __restrict__ bhh0,
                 const float* __restrict__ WihL, const float* __restrict__ WhhL,
                 const float* __restrict__ bihL, const float* __restrict__ bhhL,
                 const float* __restrict__ fcw,  const float* __restrict__ fcb,
                 float* __restrict__ out)         // [2048] f32
{
    const int tid  = threadIdx.x;
    const int lay  = tid >> 6;          // wave = layer
    const int lane = tid & 63;
    const int lb   = lane & 15;         // A-row-in-tile / B-col / C-col
    const int lg   = lane >> 4;         // k-octet (A/B) / C row group
    const int b0   = blockIdx.x * NB;
    const int lbc  = (lb < NB) ? lb : (NB - 1);

    // h_lds[layer][parity][batchcol][k]: k=50 is the constant-1 bias slot.
    __shared__ __align__(16) _Float16 h_lds[NLAY][2][16][72];
    __shared__ float x_row[NB][516];    // stride 516 floats: (4*lb'+t)%32 banks, <=2-way

    const float* Wih = (lay==0) ? Wih0 : WihL + (size_t)(lay-1)*G3*HDIM;
    const float* Whh = (lay==0) ? Whh0 : WhhL + (size_t)(lay-1)*G3*HDIM;
    const float* bih = (lay==0) ? bih0 : bihL + (lay-1)*G3;
    const float* bhh = (lay==0) ? bhh0 : bhhL + (lay-1)*G3;

    // ---- A fragments: 12 tiles x 2 k-tiles x {hh, ih}, biases folded at k==50 ----
    f16x8 a_hh[NT][2], a_ih[NT][2];
#pragma unroll
    for (int mt = 0; mt < NT; ++mt) {
        const int  ur = (mt & 3)*16 + lb;          // row within gate block
        const bool rv = ur < HDIM;
        const int  gr = 50*(mt >> 2) + (rv ? ur : 0);
#pragma unroll
        for (int kt = 0; kt < 2; ++kt) {
            f16x8 fh, fi;
#pragma unroll
            for (int j = 0; j < 8; ++j) {
                const int k = 32*kt + 8*lg + j;
                float vh = 0.f, vi = 0.f;
                if (rv) {
                    if (k < HDIM)       vh = Whh[gr*HDIM + k];
                    else if (k == HDIM) vh = bhh[gr];
                    if (lay == 0) {
                        if (kt == 0 && k == 0)      vi = Wih[gr];
                        else if (kt == 0 && k == 1) vi = bih[gr];
                    } else {
                        if (k < HDIM)       vi = Wih[gr*HDIM + k];
                        else if (k == HDIM) vi = bih[gr];
                    }
                }
                fh[j] = (_Float16)vh; fi[j] = (_Float16)vi;
            }
            a_hh[mt][kt] = fh; a_ih[mt][kt] = fi;
        }
    }

    // ---- stage x rows; init h_lds (h=0, bias slot 50 = 1.0, both parities) ----
    for (int k = tid; k < NB*TSEQ; k += 256)
        x_row[k >> 9][k & 511] = xin[(size_t)(b0 + (k >> 9))*TSEQ + (k & 511)];
    for (int k = tid; k < NLAY*2*16*72; k += 256)
        ((_Float16*)h_lds)[k] = (_Float16)(((k % 72) == HDIM) ? 1.f : 0.f);

    float hold[4][4];                   // persistent h, C-layout (f32)
#pragma unroll
    for (int m = 0; m < 4; ++m)
#pragma unroll
        for (int i = 0; i < 4; ++i) hold[m][i] = 0.f;
    __syncthreads();

    // initial B-fragments (parity 1 = "step -1" state: h=0 + bias slot)
    f16x8 bh0 = *(const f16x8*)&h_lds[lay][1][lb][8*lg];
    f16x8 bh1 = *(const f16x8*)&h_lds[lay][1][lb][32 + 8*lg];
    f16x8 bx0{}, bx1{};
    if (lay == 0) {
        const float xv = x_row[lbc][0];
#pragma unroll
        for (int j = 0; j < 8; ++j) bx0[j] = (_Float16)0.f;
        if (lg == 0) { bx0[0] = (_Float16)xv; bx0[1] = (_Float16)1.f; }
    } else {
        bx0 = *(const f16x8*)&h_lds[lay-1][1][lb][8*lg];
        bx1 = *(const f16x8*)&h_lds[lay-1][1][lb][32 + 8*lg];
    }

    for (int s = 0; s < TSEQ + NLAY - 1; ++s) {
        const int t = s - lay;
        if (t >= 0 && t < TSEQ) {
            f32x4 acc[NT], accx[4];     // acc: gh+gx (r,z) / gh (n); accx: gx (n)
#pragma unroll
            for (int mt = 0; mt < NT; ++mt) acc[mt] = f32x4{0.f,0.f,0.f,0.f};
#pragma unroll
            for (int m = 0; m < 4; ++m) accx[m] = f32x4{0.f,0.f,0.f,0.f};

#pragma unroll
            for (int mt = 0; mt < NT; ++mt) acc[mt]  = MFMA(a_hh[mt][0], bh0, acc[mt]);
#pragma unroll
            for (int mt = 0; mt < 8; ++mt)  acc[mt]  = MFMA(a_ih[mt][0], bx0, acc[mt]);
#pragma unroll
            for (int m = 0; m < 4; ++m)     accx[m]  = MFMA(a_ih[8+m][0], bx0, accx[m]);
#pragma unroll
            for (int mt = 0; mt < NT; ++mt) acc[mt]  = MFMA(a_hh[mt][1], bh1, acc[mt]);
            if (lay != 0) {
#pragma unroll
                for (int mt = 0; mt < 8; ++mt) acc[mt] = MFMA(a_ih[mt][1], bx1, acc[mt]);
#pragma unroll
                for (int m = 0; m < 4; ++m)    accx[m] = MFMA(a_ih[8+m][1], bx1, accx[m]);
            }

            // sigmoids for r (tiles 0-3) and z (tiles 4-7), in place
#pragma unroll
            for (int mt = 0; mt < 8; ++mt) {
#pragma unroll
                for (int i = 0; i < 4; ++i) {
                    if (((mt & 3) == 3) && i >= 2) continue;   // u>=50 for all lg
                    acc[mt][i] = __builtin_amdgcn_rcpf(1.f + __expf(-acc[mt][i]));
                }
            }

            // n gate + h update (all-register), publish h' to LDS
            _Float16* hrow = &h_lds[lay][s & 1][lb][0];
#pragma unroll
            for (int m = 0; m < 4; ++m) {
                float hp[4];
#pragma unroll
                for (int i = 0; i < 4; ++i) {
                    if (m == 3 && i >= 2) { hp[i] = 0.f; continue; }
                    const float r  = acc[m][i];
                    const float z  = acc[4+m][i];
                    const float vp = accx[m][i] + r * acc[8+m][i];
                    const float e2 = __expf(2.f * vp);
                    const float n  = 1.f - 2.f*__builtin_amdgcn_rcpf(e2 + 1.f); // tanh
                    const float h  = fmaf(z, hold[m][i] - n, n);                // (1-z)n+zh
                    hold[m][i] = h;
                    hp[i] = h;
                }
#pragma unroll
                for (int ip = 0; ip < 2; ++ip) {
                    if (m == 3 && ip == 1) continue;           // u>=50 always
                    if (m != 3 || lg == 0) {                   // (3,0) valid only lg==0
                        f16x2 q; q[0] = (_Float16)hp[2*ip]; q[1] = (_Float16)hp[2*ip+1];
                        *(f16x2*)&hrow[16*m + 4*lg + 2*ip] = q;
                    }
                }
            }
        }
        __syncthreads();   // h(t) for all layers published in buf[s&1]

        const int pb = s & 1;
        bh0 = *(const f16x8*)&h_lds[lay][pb][lb][8*lg];
        bh1 = *(const f16x8*)&h_lds[lay][pb][lb][32 + 8*lg];
        if (lay == 0) {
            const int tt = (s+1 < TSEQ) ? s+1 : TSEQ-1;
            const float xv = x_row[lbc][tt];
#pragma unroll
            for (int j = 0; j < 8; ++j) bx0[j] = (_Float16)0.f;
            if (lg == 0) { bx0[0] = (_Float16)xv; bx0[1] = (_Float16)1.f; }
        } else {
            bx0 = *(const f16x8*)&h_lds[lay-1][pb][lb][8*lg];
            bx1 = *(const f16x8*)&h_lds[lay-1][pb][lb][32 + 8*lg];
        }
    }

    // ---- fused FC + sigmoid on layer-3 final h (written at s=514 -> parity 0) ----
    if (tid < NB) {
        float sacc = fcb[0];
#pragma unroll
        for (int j = 0; j < HDIM; ++j)
            sacc = fmaf((float)h_lds[NLAY-1][0][tid][j], fcw[j], sacc);
        out[b0 + tid] = __builtin_amdgcn_rcpf(1.f + __expf(-sacc));
    }
}

extern "C" void kernel_launch(void* const* d_in, const int* in_sizes, int n_in,
                              void* d_out, int out_size, void* d_ws, size_t ws_size,
                              hipStream_t stream) {
    const float* x     = (const float*)d_in[0];
    const float* W_ih0 = (const float*)d_in[1];
    const float* W_hh0 = (const float*)d_in[2];
    const float* b_ih0 = (const float*)d_in[3];
    const float* b_hh0 = (const float*)d_in[4];
    const float* W_ih  = (const float*)d_in[5];
    const float* W_hh  = (const float*)d_in[6];
    const float* b_ih  = (const float*)d_in[7];
    const float* b_hh  = (const float*)d_in[8];
    const float* fc_w  = (const float*)d_in[9];
    const float* fc_b  = (const float*)d_in[10];
    float* out = (float*)d_out;

    dim3 grid(BATCH / NB), block(256);
    gru_fused1w<<<grid, block, 0, stream>>>(
        x, W_ih0, W_hh0, b_ih0, b_hh0,
        W_ih, W_hh, b_ih, b_hh, fc_w, fc_b, out);
}